// Round 3
// baseline (657.679 us; speedup 1.0000x reference)
//
#include <hip/hip_runtime.h>
#include <hip/hip_bf16.h>
#include <math.h>

#define NROW 16384
#define NH 8
#define DD 1024
#define BM 128
#define BN 128
#define BK 64

typedef __attribute__((ext_vector_type(8))) short bf16x8;
typedef __attribute__((ext_vector_type(4))) float f32x4;

__device__ __forceinline__ unsigned short f2bf(float f) {
  unsigned int u = __float_as_uint(f);
  u += 0x7fff + ((u >> 16) & 1);   // round-to-nearest-even
  return (unsigned short)(u >> 16);
}

__device__ __forceinline__ void gll16(const void* g, void* l) {
  __builtin_amdgcn_global_load_lds(
      (const __attribute__((address_space(1))) void*)g,
      (__attribute__((address_space(3))) void*)l, 16, 0, 0);
}

// ---- W f32 -> bf16 ----
__global__ __launch_bounds__(256) void cvt_kernel(const float* __restrict__ in,
                                                  unsigned short* __restrict__ out, int n) {
  int idx = blockIdx.x * 256 + threadIdx.x;
  int stride = gridDim.x * 256;
  for (int i = idx * 8; i < n; i += stride * 8) {
    float4 a = *(const float4*)(in + i);
    float4 b = *(const float4*)(in + i + 4);
    ushort4 o0 = { f2bf(a.x), f2bf(a.y), f2bf(a.z), f2bf(a.w) };
    ushort4 o1 = { f2bf(b.x), f2bf(b.y), f2bf(b.z), f2bf(b.w) };
    *(ushort4*)(out + i) = o0;
    *(ushort4*)(out + i + 4) = o1;
  }
}

// ---- cosine-sim softmax s[n,h] (f32 exact) + x -> bf16 side product ----
__global__ __launch_bounds__(256) void skern(const float* __restrict__ x,
                                             const float* __restrict__ P,
                                             float* __restrict__ s_out,
                                             unsigned short* __restrict__ xb) {
  __shared__ float Pl[NH * DD];
  __shared__ float pn[NH];
  int tid = threadIdx.x;
  for (int i = tid * 4; i < NH * DD; i += 1024)
    *(float4*)&Pl[i] = *(const float4*)&P[i];
  __syncthreads();
  int wid = tid >> 6, lane = tid & 63;
  #pragma unroll
  for (int hh = 0; hh < 2; ++hh) {
    int h = wid * 2 + hh;
    float acc = 0.f;
    #pragma unroll
    for (int d = 0; d < DD; d += 256) {
      float4 v = *(float4*)&Pl[h * DD + d + lane * 4];
      acc += v.x * v.x + v.y * v.y + v.z * v.z + v.w * v.w;
    }
    #pragma unroll
    for (int off = 1; off < 64; off <<= 1) acc += __shfl_xor(acc, off);
    if (lane == 0) pn[h] = sqrtf(acc);
  }
  __syncthreads();
  for (int row = blockIdx.x * 4 + wid; row < NROW; row += gridDim.x * 4) {
    const float* xr = x + (size_t)row * DD;
    float xn2 = 0.f;
    float dot[NH];
    #pragma unroll
    for (int h = 0; h < NH; ++h) dot[h] = 0.f;
    #pragma unroll
    for (int j = 0; j < 4; ++j) {
      int d = lane * 4 + j * 256;
      float4 v = *(const float4*)&xr[d];
      xn2 += v.x * v.x + v.y * v.y + v.z * v.z + v.w * v.w;
      #pragma unroll
      for (int h = 0; h < NH; ++h) {
        float4 p = *(float4*)&Pl[h * DD + d];
        dot[h] += v.x * p.x + v.y * p.y + v.z * p.z + v.w * p.w;
      }
      ushort4 o = { f2bf(v.x), f2bf(v.y), f2bf(v.z), f2bf(v.w) };
      *(ushort4*)&xb[(size_t)row * DD + d] = o;
    }
    #pragma unroll
    for (int off = 1; off < 64; off <<= 1) {
      xn2 += __shfl_xor(xn2, off);
      #pragma unroll
      for (int h = 0; h < NH; ++h) dot[h] += __shfl_xor(dot[h], off);
    }
    if (lane == 0) {
      float xn = sqrtf(xn2);
      float sh[NH], m = -1e30f;
      #pragma unroll
      for (int h = 0; h < NH; ++h) {
        sh[h] = 10.f * dot[h] / fmaxf(xn * pn[h], 1e-8f);
        m = fmaxf(m, sh[h]);
      }
      float sum = 0.f;
      #pragma unroll
      for (int h = 0; h < NH; ++h) { sh[h] = __expf(sh[h] - m); sum += sh[h]; }
      float inv = 1.f / sum;
      float4 o0 = { sh[0] * inv, sh[1] * inv, sh[2] * inv, sh[3] * inv };
      float4 o1 = { sh[4] * inv, sh[5] * inv, sh[6] * inv, sh[7] * inv };
      *(float4*)&s_out[(size_t)row * NH] = o0;
      *(float4*)&s_out[(size_t)row * NH + 4] = o1;
    }
  }
}

// ---- fused GEMM: out = x + sum_h s[n,h] * (x @ W[h]^T + b[h]) ----
// T2 swizzle: LDS[r][c] holds global[r][c ^ ((r&7)*8)] (elements). Staging keeps
// global_load_lds dest linear and pre-swizzles the SOURCE column; reads XOR the
// column. row&7 == lane&7 for all fragment reads, lane>>3 for staging rows.
__global__ __launch_bounds__(256, 4) void gemm_kern(
    const unsigned short* __restrict__ xb,   // [NROW][DD] bf16
    const unsigned short* __restrict__ Wb,   // [NH][DD][DD] bf16, [h][e][d]
    const float* __restrict__ s,             // [NROW][NH]
    const float* __restrict__ x,             // residual, f32
    const float* __restrict__ bias,          // [NH][DD]
    float* __restrict__ out)
{
  __shared__ unsigned short As[BM * BK];   // 16 KB
  __shared__ unsigned short Bs[BN * BK];   // 16 KB
  __shared__ float sl[BM * NH];            // 4 KB
  __shared__ float bl[NH * BN];            // 4 KB

  int bid = blockIdx.x;
  int mt = bid >> 3, nt = bid & 7;   // XCD x (bid%8) keeps col-panel x's 2MB W slice L2-resident
  int row0 = mt * BM, col0 = nt * BN;
  int tid = threadIdx.x, wid = tid >> 6, lane = tid & 63;
  int wr = (wid >> 1) * 64, wc = (wid & 1) * 64;

  ((float4*)sl)[tid] = ((const float4*)(s + (size_t)row0 * NH))[tid];
  { int hh = tid >> 5, c4 = (tid & 31) * 4;
    *(float4*)&bl[hh * BN + c4] = *(const float4*)&bias[hh * DD + col0 + c4]; }

  int sr = wid * 32 + (lane >> 3);                  // staging row (chunk 0)
  int sc = 8 * ((lane & 7) ^ (lane >> 3));          // pre-swizzled source col (elems)
  const unsigned short* Ab = xb + (size_t)row0 * DD;

  f32x4 tot[4][4];
  #pragma unroll
  for (int m = 0; m < 4; ++m)
    #pragma unroll
    for (int n = 0; n < 4; ++n)
      tot[m][n] = (f32x4){0.f, 0.f, 0.f, 0.f};

  int swz = (lane & 7) << 3;                        // read-side column XOR

  #pragma unroll 1
  for (int h = 0; h < NH; ++h) {
    const unsigned short* Bb = Wb + ((size_t)h * DD + col0) * DD;
    f32x4 part[4][4];
    #pragma unroll
    for (int m = 0; m < 4; ++m)
      #pragma unroll
      for (int n = 0; n < 4; ++n)
        part[m][n] = (f32x4){0.f, 0.f, 0.f, 0.f};

    #pragma unroll 1
    for (int dt = 0; dt < 16; ++dt) {
      int d0 = dt * BK;
      #pragma unroll
      for (int c = 0; c < 4; ++c) {
        int r = sr + c * 8;
        gll16(Ab + (size_t)r * DD + d0 + sc, &As[(wid * 32 + c * 8) * BK]);
        gll16(Bb + (size_t)r * DD + d0 + sc, &Bs[(wid * 32 + c * 8) * BK]);
      }
      __syncthreads();
      #pragma unroll
      for (int ks = 0; ks < 2; ++ks) {
        int kb = (ks * 32 + (lane >> 4) * 8) ^ swz;
        bf16x8 a[4], b[4];
        #pragma unroll
        for (int m = 0; m < 4; ++m)
          a[m] = *(const bf16x8*)&As[(wr + m * 16 + (lane & 15)) * BK + kb];
        #pragma unroll
        for (int n = 0; n < 4; ++n)
          b[n] = *(const bf16x8*)&Bs[(wc + n * 16 + (lane & 15)) * BK + kb];
        #pragma unroll
        for (int m = 0; m < 4; ++m)
          #pragma unroll
          for (int n = 0; n < 4; ++n)
            part[m][n] = __builtin_amdgcn_mfma_f32_16x16x32_bf16(a[m], b[n], part[m][n], 0, 0, 0);
      }
      __syncthreads();
    }
    // h-boundary: tot += s[row,h] * part
    #pragma unroll
    for (int m = 0; m < 4; ++m) {
      #pragma unroll
      for (int r = 0; r < 4; ++r) {
        float sv = sl[(wr + m * 16 + (lane >> 4) * 4 + r) * NH + h];
        #pragma unroll
        for (int n = 0; n < 4; ++n)
          tot[m][n][r] += sv * part[m][n][r];
      }
    }
  }

  // epilogue: + sum_h s*b + residual x
  #pragma unroll
  for (int m = 0; m < 4; ++m) {
    #pragma unroll
    for (int r = 0; r < 4; ++r) {
      int rl = wr + m * 16 + (lane >> 4) * 4 + r;
      size_t grow = (size_t)(row0 + rl);
      float4 sA = *(float4*)&sl[rl * NH];
      float4 sB = *(float4*)&sl[rl * NH + 4];
      #pragma unroll
      for (int n = 0; n < 4; ++n) {
        int cl = wc + n * 16 + (lane & 15);
        size_t gidx = grow * DD + col0 + cl;
        float bv = sA.x * bl[0 * BN + cl] + sA.y * bl[1 * BN + cl]
                 + sA.z * bl[2 * BN + cl] + sA.w * bl[3 * BN + cl]
                 + sB.x * bl[4 * BN + cl] + sB.y * bl[5 * BN + cl]
                 + sB.z * bl[6 * BN + cl] + sB.w * bl[7 * BN + cl];
        out[gidx] = tot[m][n][r] + bv + x[gidx];
      }
    }
  }
}

extern "C" void kernel_launch(void* const* d_in, const int* in_sizes, int n_in,
                              void* d_out, int out_size, void* d_ws, size_t ws_size,
                              hipStream_t stream) {
  const float* x  = (const float*)d_in[0];
  const float* P  = (const float*)d_in[1];
  const float* W  = (const float*)d_in[2];
  const float* b  = (const float*)d_in[3];
  float* out = (float*)d_out;
  char* ws = (char*)d_ws;
  float* s           = (float*)ws;                                   // 512 KB
  unsigned short* Wb = (unsigned short*)(ws + (1 << 20));            // 16 MB
  unsigned short* xb = (unsigned short*)(ws + (1 << 20) + NH * DD * DD * 2); // 32 MB

  cvt_kernel<<<1024, 256, 0, stream>>>(W, Wb, NH * DD * DD);
  skern<<<1024, 256, 0, stream>>>(x, P, s, xb);
  gemm_kern<<<1024, 256, 0, stream>>>(xb, Wb, s, x, b, out);
}

// Round 6
// 457.488 us; speedup vs baseline: 1.4376x; 1.4376x over previous
//
#include <hip/hip_runtime.h>
#include <hip/hip_bf16.h>
#include <math.h>

#define NROW 16384
#define NH 8
#define DD 1024
#define BM 128
#define BN 128
#define BK 64

typedef __attribute__((ext_vector_type(8))) short bf16x8;
typedef __attribute__((ext_vector_type(4))) float f32x4;

__device__ __forceinline__ unsigned short f2bf(float f) {
  unsigned int u = __float_as_uint(f);
  u += 0x7fff + ((u >> 16) & 1);   // round-to-nearest-even
  return (unsigned short)(u >> 16);
}

__device__ __forceinline__ void gll16(const void* g, void* l) {
  __builtin_amdgcn_global_load_lds(
      (const __attribute__((address_space(1))) void*)g,
      (__attribute__((address_space(3))) void*)l, 16, 0, 0);
}

// ---- W f32 -> bf16 ----
__global__ __launch_bounds__(256) void cvt_kernel(const float* __restrict__ in,
                                                  unsigned short* __restrict__ out, int n) {
  int idx = blockIdx.x * 256 + threadIdx.x;
  int stride = gridDim.x * 256;
  for (int i = idx * 8; i < n; i += stride * 8) {
    float4 a = *(const float4*)(in + i);
    float4 b = *(const float4*)(in + i + 4);
    ushort4 o0 = { f2bf(a.x), f2bf(a.y), f2bf(a.z), f2bf(a.w) };
    ushort4 o1 = { f2bf(b.x), f2bf(b.y), f2bf(b.z), f2bf(b.w) };
    *(ushort4*)(out + i) = o0;
    *(ushort4*)(out + i + 4) = o1;
  }
}

// ---- cosine-sim softmax s[n,h] (f32 exact) + x -> bf16 side product ----
__global__ __launch_bounds__(256) void skern(const float* __restrict__ x,
                                             const float* __restrict__ P,
                                             float* __restrict__ s_out,
                                             unsigned short* __restrict__ xb) {
  __shared__ float Pl[NH * DD];
  __shared__ float pn[NH];
  int tid = threadIdx.x;
  for (int i = tid * 4; i < NH * DD; i += 1024)
    *(float4*)&Pl[i] = *(const float4*)&P[i];
  __syncthreads();
  int wid = tid >> 6, lane = tid & 63;
  #pragma unroll
  for (int hh = 0; hh < 2; ++hh) {
    int h = wid * 2 + hh;
    float acc = 0.f;
    #pragma unroll
    for (int d = 0; d < DD; d += 256) {
      float4 v = *(float4*)&Pl[h * DD + d + lane * 4];
      acc += v.x * v.x + v.y * v.y + v.z * v.z + v.w * v.w;
    }
    #pragma unroll
    for (int off = 1; off < 64; off <<= 1) acc += __shfl_xor(acc, off);
    if (lane == 0) pn[h] = sqrtf(acc);
  }
  __syncthreads();
  for (int row = blockIdx.x * 4 + wid; row < NROW; row += gridDim.x * 4) {
    const float* xr = x + (size_t)row * DD;
    float xn2 = 0.f;
    float dot[NH];
    #pragma unroll
    for (int h = 0; h < NH; ++h) dot[h] = 0.f;
    #pragma unroll
    for (int j = 0; j < 4; ++j) {
      int d = lane * 4 + j * 256;
      float4 v = *(const float4*)&xr[d];
      xn2 += v.x * v.x + v.y * v.y + v.z * v.z + v.w * v.w;
      #pragma unroll
      for (int h = 0; h < NH; ++h) {
        float4 p = *(float4*)&Pl[h * DD + d];
        dot[h] += v.x * p.x + v.y * p.y + v.z * p.z + v.w * p.w;
      }
      ushort4 o = { f2bf(v.x), f2bf(v.y), f2bf(v.z), f2bf(v.w) };
      *(ushort4*)&xb[(size_t)row * DD + d] = o;
    }
    #pragma unroll
    for (int off = 1; off < 64; off <<= 1) {
      xn2 += __shfl_xor(xn2, off);
      #pragma unroll
      for (int h = 0; h < NH; ++h) dot[h] += __shfl_xor(dot[h], off);
    }
    if (lane == 0) {
      float xn = sqrtf(xn2);
      float sh[NH], m = -1e30f;
      #pragma unroll
      for (int h = 0; h < NH; ++h) {
        sh[h] = 10.f * dot[h] / fmaxf(xn * pn[h], 1e-8f);
        m = fmaxf(m, sh[h]);
      }
      float sum = 0.f;
      #pragma unroll
      for (int h = 0; h < NH; ++h) { sh[h] = __expf(sh[h] - m); sum += sh[h]; }
      float inv = 1.f / sum;
      float4 o0 = { sh[0] * inv, sh[1] * inv, sh[2] * inv, sh[3] * inv };
      float4 o1 = { sh[4] * inv, sh[5] * inv, sh[6] * inv, sh[7] * inv };
      *(float4*)&s_out[(size_t)row * NH] = o0;
      *(float4*)&s_out[(size_t)row * NH + 4] = o1;
    }
  }
}

// ---- fused GEMM: out = x + sum_h s[n,h] * (x @ W[h]^T + b[h]) ----
// T2 swizzle: LDS[r][c] holds global[r][c ^ ((r&7)*8)] (elements). Staging keeps
// global_load_lds dest linear and pre-swizzles the SOURCE column; reads XOR the
// column. Verified R3: conflicts 1.017e8 -> 1.05e6.
// launch_bounds(256,2): (256,4) capped VGPR at 64 -> accumulator spills,
// WRITE_SIZE 8x (R3). Accs need ~128 regs + addressing.
__global__ __launch_bounds__(256, 2) void gemm_kern(
    const unsigned short* __restrict__ xb,   // [NROW][DD] bf16
    const unsigned short* __restrict__ Wb,   // [NH][DD][DD] bf16, [h][e][d]
    const float* __restrict__ s,             // [NROW][NH]
    const float* __restrict__ x,             // residual, f32
    const float* __restrict__ bias,          // [NH][DD]
    float* __restrict__ out)
{
  __shared__ unsigned short As[BM * BK];   // 16 KB
  __shared__ unsigned short Bs[BN * BK];   // 16 KB
  __shared__ float sl[BM * NH];            // 4 KB
  __shared__ float bl[NH * BN];            // 4 KB

  int bid = blockIdx.x;
  int mt = bid >> 3, nt = bid & 7;   // XCD x (bid%8) keeps col-panel x's 2MB W slice L2-resident
  int row0 = mt * BM, col0 = nt * BN;
  int tid = threadIdx.x, wid = tid >> 6, lane = tid & 63;
  int wr = (wid >> 1) * 64, wc = (wid & 1) * 64;

  ((float4*)sl)[tid] = ((const float4*)(s + (size_t)row0 * NH))[tid];
  { int hh = tid >> 5, c4 = (tid & 31) * 4;
    *(float4*)&bl[hh * BN + c4] = *(const float4*)&bias[hh * DD + col0 + c4]; }

  int sr = wid * 32 + (lane >> 3);                  // staging row (chunk 0)
  int sc = 8 * ((lane & 7) ^ (lane >> 3));          // pre-swizzled source col (elems)
  const unsigned short* Ab = xb + (size_t)row0 * DD;

  f32x4 tot[4][4];
  #pragma unroll
  for (int m = 0; m < 4; ++m)
    #pragma unroll
    for (int n = 0; n < 4; ++n)
      tot[m][n] = (f32x4){0.f, 0.f, 0.f, 0.f};

  int swz = (lane & 7) << 3;                        // read-side column XOR

  #pragma unroll 1
  for (int h = 0; h < NH; ++h) {
    const unsigned short* Bb = Wb + ((size_t)h * DD + col0) * DD;
    f32x4 part[4][4];
    #pragma unroll
    for (int m = 0; m < 4; ++m)
      #pragma unroll
      for (int n = 0; n < 4; ++n)
        part[m][n] = (f32x4){0.f, 0.f, 0.f, 0.f};

    #pragma unroll 1
    for (int dt = 0; dt < 16; ++dt) {
      int d0 = dt * BK;
      #pragma unroll
      for (int c = 0; c < 4; ++c) {
        int r = sr + c * 8;
        gll16(Ab + (size_t)r * DD + d0 + sc, &As[(wid * 32 + c * 8) * BK]);
        gll16(Bb + (size_t)r * DD + d0 + sc, &Bs[(wid * 32 + c * 8) * BK]);
      }
      __syncthreads();
      #pragma unroll
      for (int ks = 0; ks < 2; ++ks) {
        int kb = (ks * 32 + (lane >> 4) * 8) ^ swz;
        bf16x8 a[4], b[4];
        #pragma unroll
        for (int m = 0; m < 4; ++m)
          a[m] = *(const bf16x8*)&As[(wr + m * 16 + (lane & 15)) * BK + kb];
        #pragma unroll
        for (int n = 0; n < 4; ++n)
          b[n] = *(const bf16x8*)&Bs[(wc + n * 16 + (lane & 15)) * BK + kb];
        #pragma unroll
        for (int m = 0; m < 4; ++m)
          #pragma unroll
          for (int n = 0; n < 4; ++n)
            part[m][n] = __builtin_amdgcn_mfma_f32_16x16x32_bf16(a[m], b[n], part[m][n], 0, 0, 0);
      }
      __syncthreads();
    }
    // h-boundary: tot += s[row,h] * part
    #pragma unroll
    for (int m = 0; m < 4; ++m) {
      #pragma unroll
      for (int r = 0; r < 4; ++r) {
        float sv = sl[(wr + m * 16 + (lane >> 4) * 4 + r) * NH + h];
        #pragma unroll
        for (int n = 0; n < 4; ++n)
          tot[m][n][r] += sv * part[m][n][r];
      }
    }
  }

  // epilogue: + sum_h s*b + residual x
  #pragma unroll
  for (int m = 0; m < 4; ++m) {
    #pragma unroll
    for (int r = 0; r < 4; ++r) {
      int rl = wr + m * 16 + (lane >> 4) * 4 + r;
      size_t grow = (size_t)(row0 + rl);
      float4 sA = *(float4*)&sl[rl * NH];
      float4 sB = *(float4*)&sl[rl * NH + 4];
      #pragma unroll
      for (int n = 0; n < 4; ++n) {
        int cl = wc + n * 16 + (lane & 15);
        size_t gidx = grow * DD + col0 + cl;
        float bv = sA.x * bl[0 * BN + cl] + sA.y * bl[1 * BN + cl]
                 + sA.z * bl[2 * BN + cl] + sA.w * bl[3 * BN + cl]
                 + sB.x * bl[4 * BN + cl] + sB.y * bl[5 * BN + cl]
                 + sB.z * bl[6 * BN + cl] + sB.w * bl[7 * BN + cl];
        out[gidx] = tot[m][n][r] + bv + x[gidx];
      }
    }
  }
}

extern "C" void kernel_launch(void* const* d_in, const int* in_sizes, int n_in,
                              void* d_out, int out_size, void* d_ws, size_t ws_size,
                              hipStream_t stream) {
  const float* x  = (const float*)d_in[0];
  const float* P  = (const float*)d_in[1];
  const float* W  = (const float*)d_in[2];
  const float* b  = (const float*)d_in[3];
  float* out = (float*)d_out;
  char* ws = (char*)d_ws;
  float* s           = (float*)ws;                                   // 512 KB
  unsigned short* Wb = (unsigned short*)(ws + (1 << 20));            // 16 MB
  unsigned short* xb = (unsigned short*)(ws + (1 << 20) + NH * DD * DD * 2); // 32 MB

  cvt_kernel<<<1024, 256, 0, stream>>>(W, Wb, NH * DD * DD);
  skern<<<1024, 256, 0, stream>>>(x, P, s, xb);
  gemm_kern<<<1024, 256, 0, stream>>>(xb, Wb, s, x, b, out);
}